// Round 10
// baseline (300.614 us; speedup 1.0000x reference)
//
#include <hip/hip_runtime.h>
#include <hip/hip_bf16.h>

// ON-LSTM cell fused, R10: 256x256 16x16x32 MFMA. A-operand loaded DIRECTLY
// global->registers (no LDS for A: removes 128KB/tile of redundant LDS reads
// + all A staging; A is read-only so gA loads have no ordering constraints,
// compiler inserts counted vmcnt waits). B stays LDS-staged (XOR-swizzled,
// double-buffered). 8 phases/tile (1 m-frag x K=64 = 8 MFMA each), A-frag
// regs double-buffered afE/afO (16 VGPR), 2 barriers/tile.
//
// Race audit (B only; A/W read-only):
//  - p3-end lgkm0+BAR: all waves' LDB(cur) reads done -> stage B(t+2)->cur
//    at p4/p5 safe.
//  - B(t+1) staged t-1.p4/p5; every wave's compiler-inserted vmcnt before
//    MF(m1)@t.p1 (for gA(m1)@t.p0, younger) retires all older vmem incl.
//    those stages; t.p7-end BAR publishes -> t+1.p0 LDB safe.
//  - B(t+2) consumed t+2.p0: retired by t+1's auto-waits, published t+1.p7.
//  - Tail wraps ((t+2)&31) stage / gA((t+1)&31): write/read valid memory,
//    never consumed. Benign.

#define B_ROWS 8192
#define IN_DIM 1024
#define H_DIM  1024
#define NCHUNK 16
#define K_TOT  2048

#define BM   256
#define BN   256
#define BK   64
#define NKT  (K_TOT / BK)   // 32 K-tiles
#define THREADS 512

#define A_PACK_BYTES ((size_t)B_ROWS * K_TOT * 2)        // 32 MiB
#define W_PACK_BYTES ((size_t)16 * 256 * K_TOT * 2)      // 16 MiB

typedef __attribute__((ext_vector_type(4))) float  f32x4;
typedef __bf16 bf16x8 __attribute__((ext_vector_type(8)));

__device__ __forceinline__ float sigmoidf_(float x) {
    return 1.0f / (1.0f + __expf(-x));
}
__device__ __forceinline__ float tanhf_(float x) {
    float e = __expf(-2.0f * fabsf(x));
    float t = (1.0f - e) / (1.0f + e);
    return copysignf(t, x);
}

__device__ __forceinline__ void gload16(const __bf16* gsrc, __bf16* lds_dst) {
    __builtin_amdgcn_global_load_lds(
        (const __attribute__((address_space(1))) unsigned int*)gsrc,
        (__attribute__((address_space(3))) unsigned int*)lds_dst, 16, 0, 0);
}

__device__ __forceinline__ bf16x8 cvt8(f32x4 v0, f32x4 v1) {
    bf16x8 o;
    o[0] = (__bf16)v0.x; o[1] = (__bf16)v0.y; o[2] = (__bf16)v0.z; o[3] = (__bf16)v0.w;
    o[4] = (__bf16)v1.x; o[5] = (__bf16)v1.y; o[6] = (__bf16)v1.z; o[7] = (__bf16)v1.w;
    return o;
}

// ---- fused pack: blocks [0,8192) pack A rows; [8192,12288) pack W rows ----
__global__ __launch_bounds__(256)
void pack_AW(const float* __restrict__ x, const float* __restrict__ hx,
             const float* __restrict__ W_ih, const float* __restrict__ W_hh,
             __bf16* __restrict__ Abf, __bf16* __restrict__ Wp)
{
    const int bid = blockIdx.x;
    const int c8  = threadIdx.x << 3;
    if (bid < B_ROWS) {
        const float* src = (c8 < IN_DIM)
            ? (x  + (size_t)bid * IN_DIM + c8)
            : (hx + (size_t)bid * IN_DIM + (c8 - IN_DIM));
        f32x4 v0 = *reinterpret_cast<const f32x4*>(src);
        f32x4 v1 = *reinterpret_cast<const f32x4*>(src + 4);
        *reinterpret_cast<bf16x8*>(Abf + (size_t)bid * K_TOT + c8) = cvt8(v0, v1);
    } else {
        const int r  = bid - B_ROWS;       // 0..4095
        const int bh = r >> 8;
        const int n  = r & 255;
        const int g  = (n >> 4) & 3;
        const int j  = (n >> 6) * 16 + (n & 15);
        const int wr = g * H_DIM + bh * 64 + j;
        const float* src = (c8 < IN_DIM)
            ? (W_ih + (size_t)wr * IN_DIM + c8)
            : (W_hh + (size_t)wr * IN_DIM + (c8 - IN_DIM));
        f32x4 v0 = *reinterpret_cast<const f32x4*>(src);
        f32x4 v1 = *reinterpret_cast<const f32x4*>(src + 4);
        *reinterpret_cast<bf16x8*>(Wp + (size_t)r * K_TOT + c8) = cvt8(v0, v1);
    }
}

// stage one 128x64 B half-tile: 2 x global_load_lds(16B)/thread, linear LDS
// dest, inverse-swizzled global source.
__device__ __forceinline__ void stage_half(const __bf16* __restrict__ gbase, int kb,
                                           __bf16* lbase, int row0, int tid) {
    #pragma unroll
    for (int i = 0; i < 2; ++i) {
        int e   = i * 4096 + tid * 8;
        int row = row0 + (e >> 6);
        int kd  = e & 63;
        gload16(gbase + (size_t)row * K_TOT + kb + (kd ^ ((row & 7) << 3)), lbase + e);
    }
}

#define SWZ(r, k) ((r) * 64 + ((k) ^ (((r) & 7) << 3)))

#define LDB(Bs) { \
    _Pragma("unroll") \
    for (int fn = 0; fn < 4; ++fn) { \
        int br = wcol + fn * 16 + lr; \
        bfr[fn][0] = *reinterpret_cast<const bf16x8*>(&(Bs)[SWZ(br, lh * 8)]); \
        bfr[fn][1] = *reinterpret_cast<const bf16x8*>(&(Bs)[SWZ(br, 32 + lh * 8)]); \
    } }

// direct global->reg A fragment (one m-frag, both k-slices)
#define GA(dst, ptr) { \
    dst[0] = *reinterpret_cast<const bf16x8*>(ptr); \
    dst[1] = *reinterpret_cast<const bf16x8*>((ptr) + 32); \
}

#define SB0 __builtin_amdgcn_sched_barrier(0)
#define LGKM0 asm volatile("s_waitcnt lgkmcnt(0)" ::: "memory")
#define BARRIER do { \
    asm volatile("" ::: "memory"); \
    __builtin_amdgcn_s_barrier(); \
    asm volatile("" ::: "memory"); \
} while (0)

// 8 MFMAs: one m-frag x all 4 n-frags x 2 k-slices (ks outer: dep distance 4)
#define MFH(m, a) { \
    __builtin_amdgcn_s_setprio(1); \
    _Pragma("unroll") \
    for (int ks = 0; ks < 2; ++ks) { \
        _Pragma("unroll") \
        for (int fn = 0; fn < 4; ++fn) { \
            acc[m][fn] = __builtin_amdgcn_mfma_f32_16x16x32_bf16(a[ks], bfr[fn][ks], acc[m][fn], 0, 0, 0); \
        } \
    } \
    __builtin_amdgcn_s_setprio(0); \
}

#define MROW (16 * K_TOT)

// One K-tile. CUR/NXT: B LDS buffers. Ab: per-lane A base for this tile.
#define TILE10(T, CUR, NXT) { \
    const __bf16* Ab  = Arow2 + (size_t)((T) & 31) * BK; \
    const __bf16* AbN = Arow2 + (size_t)(((T) + 1) & 31) * BK; \
    /* p0 */ \
    LDB(CUR); \
    GA(afO, Ab + 1 * MROW); \
    MFH(0, afE); SB0; \
    /* p1 */ \
    GA(afE, Ab + 2 * MROW); MFH(1, afO); SB0; \
    /* p2 */ \
    GA(afO, Ab + 3 * MROW); MFH(2, afE); SB0; \
    /* p3 */ \
    GA(afE, Ab + 4 * MROW); MFH(3, afO); \
    LGKM0; BARRIER; \
    /* p4 */ \
    GA(afO, Ab + 5 * MROW); \
    stage_half(Wblk, (((T) + 2) & 31) * BK, CUR,        0,   tid); \
    MFH(4, afE); SB0; \
    /* p5 */ \
    GA(afE, Ab + 6 * MROW); \
    stage_half(Wblk, (((T) + 2) & 31) * BK, CUR + 8192, 128, tid); \
    MFH(5, afO); SB0; \
    /* p6 */ \
    GA(afO, Ab + 7 * MROW); MFH(6, afE); SB0; \
    /* p7 */ \
    GA(afE, AbN); MFH(7, afO); \
    BARRIER; \
}

__global__ __launch_bounds__(THREADS, 2)
void onlstm_gemm10(const __bf16* __restrict__ Abf, const __bf16* __restrict__ Wp,
                   const float* __restrict__ cx,
                   const float* __restrict__ input_floor,
                   const float* __restrict__ forget_floor,
                   const float* __restrict__ b_ih, const float* __restrict__ b_hh,
                   float* __restrict__ out)
{
    __shared__ __align__(16) __bf16 lds[32768];          // 64 KiB: B0 B1 only
    __shared__ float ci_s[BM], cf_s[BM], bias_s[BN];

    const int tid = threadIdx.x;
    // XCD swizzle: xcd = n0&7 owns bm in [4*xcd, 4*xcd+4) x all 16 bh
    const int n0  = blockIdx.x;
    const int bm  = (n0 & 7) * 4 + ((n0 >> 3) & 3);   // 0..31
    const int bh  = n0 >> 5;                          // 0..15
    const int h0  = bh * 64;
    const int nc  = bh;

    // ---- prologue: bias + per-row cumulative-softmax master gates ----
    if (tid < BM) {
        {
            int g = (tid >> 4) & 3;
            int j = (tid >> 6) * 16 + (tid & 15);
            int wrr = g * H_DIM + h0 + j;
            bias_s[tid] = b_ih[wrr] + b_hh[wrr];
        }
        int b = bm * BM + tid;
        const int off = (nc < 8) ? 0 : 8;
        const int ic  = (nc < 8) ? nc : (nc - 8);
        const float* pin = input_floor  + (size_t)b * NCHUNK + off;
        const float* pfg = forget_floor + (size_t)b * NCHUNK + off;
        float vi[8], vf[8];
        float mi = -1e30f, mf = -1e30f;
        #pragma unroll
        for (int t = 0; t < 8; ++t) {
            vi[t] = pin[t]; vf[t] = pfg[t];
            mi = fmaxf(mi, vi[t]); mf = fmaxf(mf, vf[t]);
        }
        float si = 0.f, sf = 0.f;
        #pragma unroll
        for (int t = 0; t < 8; ++t) {
            vi[t] = __expf(vi[t] - mi); vf[t] = __expf(vf[t] - mf);
            si += vi[t]; sf += vf[t];
        }
        float pi = 0.f, pf = 0.f;
        #pragma unroll
        for (int t = 0; t < 8; ++t) { if (t <= ic) { pi += vi[t]; pf += vf[t]; } }
        float suf_i = si - pi + vi[ic];
        float suf_f = sf - pf + vf[ic];
        float civ, cfv;
        if (nc < 8) { civ = pi / si;    cfv = suf_f / sf; }
        else        { civ = suf_i / si; cfv = pf / sf;    }
        ci_s[tid] = civ; cf_s[tid] = cfv;
    }

    const __bf16* Arow = Abf + (size_t)(bm * BM) * K_TOT;
    const __bf16* Wblk = Wp  + (size_t)bh * 256 * K_TOT;
    __bf16* const B0p = lds;
    __bf16* const B1p = lds + 16384;

    const int l    = tid & 63;
    const int wid  = tid >> 6;        // 0..7
    const int wrw  = wid >> 2;        // 0..1  (M)
    const int wc   = wid & 3;         // 0..3  (N)
    const int lr   = l & 15;
    const int lh   = l >> 4;
    const int wrow = wrw * 128;
    const int wcol = wc * 64;

    // per-lane A base: row (wrow + lr), k offset lh*8; m-frag = +m*16 rows
    const __bf16* Arow2 = Arow + (size_t)(wrow + lr) * K_TOT + lh * 8;

    // prologue staging: B(0)->B0p, B(1)->B1p
    stage_half(Wblk, 0,  B0p,        0,   tid);
    stage_half(Wblk, 0,  B0p + 8192, 128, tid);
    stage_half(Wblk, BK, B1p,        0,   tid);
    stage_half(Wblk, BK, B1p + 8192, 128, tid);
    LGKM0;                                                // ci/bias ds_writes done
    asm volatile("s_waitcnt vmcnt(4)" ::: "memory");      // B(0) resident
    __builtin_amdgcn_s_barrier();
    asm volatile("" ::: "memory");

    f32x4  acc[8][4];
    #pragma unroll
    for (int i = 0; i < 8; ++i)
        #pragma unroll
        for (int j = 0; j < 4; ++j) acc[i][j] = (f32x4){0.f, 0.f, 0.f, 0.f};
    bf16x8 afE[2], afO[2];
    bf16x8 bfr[4][2];

    GA(afE, Arow2);                                       // seed m0 of tile 0

    #pragma unroll 1
    for (int it = 0; it < NKT / 2; ++it) {
        const int t = 2 * it;
        TILE10(t,     B0p, B1p);
        TILE10(t + 1, B1p, B0p);
    }

    // ---- epilogue: all 4 gates of (b,h) lane-local (fn = gate) ----
    const size_t CY_OFF = (size_t)B_ROWS * H_DIM;
    const int hcol = h0 + wc * 16 + lr;
    #pragma unroll
    for (int m = 0; m < 8; ++m) {
        #pragma unroll
        for (int r = 0; r < 4; ++r) {
            int rt = wrow + m * 16 + lh * 4 + r;
            int b  = bm * BM + rt;
            float civ = ci_s[rt], cfv = cf_s[rt];
            float ovl = cfv * civ;
            float og = acc[m][0][r] + bias_s[wcol + lr];
            float cg = acc[m][1][r] + bias_s[wcol + 16 + lr];
            float ig = acc[m][2][r] + bias_s[wcol + 32 + lr];
            float fg = acc[m][3][r] + bias_s[wcol + 48 + lr];
            float i_s = sigmoidf_(ig);
            float f_s = sigmoidf_(fg);
            float c_t = tanhf_(cg);
            float o_s = sigmoidf_(og);
            float fq = f_s * ovl + (cfv - ovl);
            float iq = i_s * ovl + (civ - ovl);
            float cxv = cx[(size_t)b * H_DIM + hcol];
            float cyv = fq * cxv + iq * c_t;
            float hyv = o_s * tanhf_(cyv);
            out[(size_t)b * H_DIM + hcol] = hyv;
            out[CY_OFF + (size_t)b * H_DIM + hcol] = cyv;
        }
    }
}

extern "C" void kernel_launch(void* const* d_in, const int* in_sizes, int n_in,
                              void* d_out, int out_size, void* d_ws, size_t ws_size,
                              hipStream_t stream) {
    const float* x            = (const float*)d_in[0];
    const float* hx           = (const float*)d_in[1];
    const float* cx           = (const float*)d_in[2];
    const float* input_floor  = (const float*)d_in[3];
    const float* forget_floor = (const float*)d_in[4];
    const float* W_ih         = (const float*)d_in[5];
    const float* b_ih         = (const float*)d_in[6];
    const float* W_hh         = (const float*)d_in[7];
    const float* b_hh         = (const float*)d_in[8];
    float* out = (float*)d_out;

    __bf16* Abf = (__bf16*)d_ws;
    __bf16* Wp  = (__bf16*)((char*)d_ws + A_PACK_BYTES);
    pack_AW<<<B_ROWS + 16 * 256, 256, 0, stream>>>(x, hx, W_ih, W_hh, Abf, Wp);
    onlstm_gemm10<<<512, THREADS, 0, stream>>>(
        Abf, Wp, cx, input_floor, forget_floor, b_ih, b_hh, out);
}

// Round 11
// 154.155 us; speedup vs baseline: 1.9501x; 1.9501x over previous
//
#include <hip/hip_runtime.h>
#include <hip/hip_bf16.h>

// ON-LSTM cell fused, R11: R7's 256x256 16x16x32 schedule + A-FRAGMENT-only
// double buffering (afE/afO, +16 regs — spill-free, unlike R9's full dbuf)
// and no inter-phase sched_barriers, so each phase's A ds_reads hoist above
// the previous phase's MFMA cluster (kills the per-phase read->stall->MFMA
// serialization diagnosed from the 4700cyc/tile ~= MFMA+LDS sum).
//   p0: LDB(cur); LDA0->afE; LDA1->afO; stage A(t+1)x2; MF0(afE); BAR
//       (BAR after MF0: every wave's last MF0 op required all bfr operands
//        -> all LDB reads retired -> B restage at p1/p2 is safe)
//   p1: LDA2->afE; stage B(t+2)h0 -> curB; MF1(afO)
//   p2: LDA3->afO; stage B(t+2)h1 -> curB; MF2(afE)
//   p3: MF3(afO); lgkm0; vmcnt(4); BAR
// vmcnt ledger (per-thread loads, induction): tile-start outstanding =
// {B(t+1):4}; +A(t+1):4 @p0, +B(t+2):4 @p1/p2 = 12; vmcnt(4) drains the 8
// oldest = B(t+1)+A(t+1), keeps B(t+2). t+1.p0 reads A(t+1)/B(t+1): drained
// and published by the p3 barrier.

#define B_ROWS 8192
#define IN_DIM 1024
#define H_DIM  1024
#define NCHUNK 16
#define K_TOT  2048

#define BM   256
#define BN   256
#define BK   64
#define NKT  (K_TOT / BK)   // 32 K-tiles
#define THREADS 512

#define A_PACK_BYTES ((size_t)B_ROWS * K_TOT * 2)        // 32 MiB
#define W_PACK_BYTES ((size_t)16 * 256 * K_TOT * 2)      // 16 MiB

typedef __attribute__((ext_vector_type(4))) float  f32x4;
typedef __bf16 bf16x8 __attribute__((ext_vector_type(8)));

__device__ __forceinline__ float sigmoidf_(float x) {
    return 1.0f / (1.0f + __expf(-x));
}
__device__ __forceinline__ float tanhf_(float x) {
    float e = __expf(-2.0f * fabsf(x));
    float t = (1.0f - e) / (1.0f + e);
    return copysignf(t, x);
}

__device__ __forceinline__ void gload16(const __bf16* gsrc, __bf16* lds_dst) {
    __builtin_amdgcn_global_load_lds(
        (const __attribute__((address_space(1))) unsigned int*)gsrc,
        (__attribute__((address_space(3))) unsigned int*)lds_dst, 16, 0, 0);
}

__device__ __forceinline__ bf16x8 cvt8(f32x4 v0, f32x4 v1) {
    bf16x8 o;
    o[0] = (__bf16)v0.x; o[1] = (__bf16)v0.y; o[2] = (__bf16)v0.z; o[3] = (__bf16)v0.w;
    o[4] = (__bf16)v1.x; o[5] = (__bf16)v1.y; o[6] = (__bf16)v1.z; o[7] = (__bf16)v1.w;
    return o;
}

// ---- fused pack: blocks [0,8192) pack A rows; [8192,12288) pack W rows ----
__global__ __launch_bounds__(256)
void pack_AW(const float* __restrict__ x, const float* __restrict__ hx,
             const float* __restrict__ W_ih, const float* __restrict__ W_hh,
             __bf16* __restrict__ Abf, __bf16* __restrict__ Wp)
{
    const int bid = blockIdx.x;
    const int c8  = threadIdx.x << 3;
    if (bid < B_ROWS) {
        const float* src = (c8 < IN_DIM)
            ? (x  + (size_t)bid * IN_DIM + c8)
            : (hx + (size_t)bid * IN_DIM + (c8 - IN_DIM));
        f32x4 v0 = *reinterpret_cast<const f32x4*>(src);
        f32x4 v1 = *reinterpret_cast<const f32x4*>(src + 4);
        *reinterpret_cast<bf16x8*>(Abf + (size_t)bid * K_TOT + c8) = cvt8(v0, v1);
    } else {
        const int r  = bid - B_ROWS;       // 0..4095
        const int bh = r >> 8;
        const int n  = r & 255;
        const int g  = (n >> 4) & 3;
        const int j  = (n >> 6) * 16 + (n & 15);
        const int wr = g * H_DIM + bh * 64 + j;
        const float* src = (c8 < IN_DIM)
            ? (W_ih + (size_t)wr * IN_DIM + c8)
            : (W_hh + (size_t)wr * IN_DIM + (c8 - IN_DIM));
        f32x4 v0 = *reinterpret_cast<const f32x4*>(src);
        f32x4 v1 = *reinterpret_cast<const f32x4*>(src + 4);
        *reinterpret_cast<bf16x8*>(Wp + (size_t)r * K_TOT + c8) = cvt8(v0, v1);
    }
}

// stage one 128x64 half-tile: 2 x global_load_lds(16B)/thread, linear LDS
// dest, inverse-swizzled global source.
__device__ __forceinline__ void stage_half(const __bf16* __restrict__ gbase, int kb,
                                           __bf16* lbase, int row0, int tid) {
    #pragma unroll
    for (int i = 0; i < 2; ++i) {
        int e   = i * 4096 + tid * 8;
        int row = row0 + (e >> 6);
        int kd  = e & 63;
        gload16(gbase + (size_t)row * K_TOT + kb + (kd ^ ((row & 7) << 3)), lbase + e);
    }
}

#define SWZ(r, k) ((r) * 64 + ((k) ^ (((r) & 7) << 3)))

#define LDB(Bs) { \
    _Pragma("unroll") \
    for (int fn = 0; fn < 4; ++fn) { \
        int br = wcol + fn * 16 + lr; \
        bfr[fn][0] = *reinterpret_cast<const bf16x8*>(&(Bs)[SWZ(br, lh * 8)]); \
        bfr[fn][1] = *reinterpret_cast<const bf16x8*>(&(Bs)[SWZ(br, 32 + lh * 8)]); \
    } }

#define LDA_TO(dst, As, q) { \
    int ar = wrow + (q) * 32 + lr; \
    dst[0][0] = *reinterpret_cast<const bf16x8*>(&(As)[SWZ(ar, lh * 8)]); \
    dst[0][1] = *reinterpret_cast<const bf16x8*>(&(As)[SWZ(ar, 32 + lh * 8)]); \
    dst[1][0] = *reinterpret_cast<const bf16x8*>(&(As)[SWZ(ar + 16, lh * 8)]); \
    dst[1][1] = *reinterpret_cast<const bf16x8*>(&(As)[SWZ(ar + 16, 32 + lh * 8)]); \
    }

#define BARRIER do { \
    asm volatile("" ::: "memory"); \
    __builtin_amdgcn_s_barrier(); \
    asm volatile("" ::: "memory"); \
} while (0)

// 16 MFMAs for quadrant q from A-fragment set a (B frags fixed in bfr).
#define MF_Q(q, a) { \
    __builtin_amdgcn_s_setprio(1); \
    _Pragma("unroll") \
    for (int ks = 0; ks < 2; ++ks) { \
        _Pragma("unroll") \
        for (int fn = 0; fn < 4; ++fn) { \
            acc[2*(q)][fn]   = __builtin_amdgcn_mfma_f32_16x16x32_bf16(a[0][ks], bfr[fn][ks], acc[2*(q)][fn],   0,0,0); \
            acc[2*(q)+1][fn] = __builtin_amdgcn_mfma_f32_16x16x32_bf16(a[1][ks], bfr[fn][ks], acc[2*(q)+1][fn], 0,0,0); \
        } \
    } \
    __builtin_amdgcn_s_setprio(0); \
}

// one K-tile: Ac/An = A cur/next buffers; Bc = B buffer for tile T (restaged
// with B(T+2) at p1/p2 after the p0-end barrier).
#define TILE11(T, Ac, An, Bc) { \
    const int t_ = (T); \
    /* p0 */ \
    LDB(Bc); \
    LDA_TO(afE, Ac, 0); \
    LDA_TO(afO, Ac, 1); \
    stage_half(Arow, ((t_ + 1) & 31) * BK, An,        0,   tid); \
    stage_half(Arow, ((t_ + 1) & 31) * BK, An + 8192, 128, tid); \
    MF_Q(0, afE); \
    BARRIER; \
    /* p1 */ \
    LDA_TO(afE, Ac, 2); \
    stage_half(Wblk, ((t_ + 2) & 31) * BK, Bc,        0,   tid); \
    MF_Q(1, afO); \
    /* p2 */ \
    LDA_TO(afO, Ac, 3); \
    stage_half(Wblk, ((t_ + 2) & 31) * BK, Bc + 8192, 128, tid); \
    MF_Q(2, afE); \
    /* p3 */ \
    MF_Q(3, afO); \
    asm volatile("s_waitcnt lgkmcnt(0)" ::: "memory"); \
    asm volatile("s_waitcnt vmcnt(4)"   ::: "memory"); \
    BARRIER; \
}

__global__ __launch_bounds__(THREADS, 2)
void onlstm_gemm11(const __bf16* __restrict__ Abf, const __bf16* __restrict__ Wp,
                   const float* __restrict__ cx,
                   const float* __restrict__ input_floor,
                   const float* __restrict__ forget_floor,
                   const float* __restrict__ b_ih, const float* __restrict__ b_hh,
                   float* __restrict__ out)
{
    __shared__ __align__(16) __bf16 lds[65536];          // 128 KiB: A0 A1 B0 B1
    __shared__ float ci_s[BM], cf_s[BM], bias_s[BN];

    const int tid = threadIdx.x;
    // XCD swizzle: xcd = n0&7 owns bm in [4*xcd, 4*xcd+4) x all 16 bh
    const int n0  = blockIdx.x;
    const int bm  = (n0 & 7) * 4 + ((n0 >> 3) & 3);   // 0..31
    const int bh  = n0 >> 5;                          // 0..15
    const int h0  = bh * 64;
    const int nc  = bh;

    // ---- prologue: bias + per-row cumulative-softmax master gates ----
    if (tid < BM) {
        {
            int g = (tid >> 4) & 3;
            int j = (tid >> 6) * 16 + (tid & 15);
            int wrr = g * H_DIM + h0 + j;
            bias_s[tid] = b_ih[wrr] + b_hh[wrr];
        }
        int b = bm * BM + tid;
        const int off = (nc < 8) ? 0 : 8;
        const int ic  = (nc < 8) ? nc : (nc - 8);
        const float* pin = input_floor  + (size_t)b * NCHUNK + off;
        const float* pfg = forget_floor + (size_t)b * NCHUNK + off;
        float vi[8], vf[8];
        float mi = -1e30f, mf = -1e30f;
        #pragma unroll
        for (int t = 0; t < 8; ++t) {
            vi[t] = pin[t]; vf[t] = pfg[t];
            mi = fmaxf(mi, vi[t]); mf = fmaxf(mf, vf[t]);
        }
        float si = 0.f, sf = 0.f;
        #pragma unroll
        for (int t = 0; t < 8; ++t) {
            vi[t] = __expf(vi[t] - mi); vf[t] = __expf(vf[t] - mf);
            si += vi[t]; sf += vf[t];
        }
        float pi = 0.f, pf = 0.f;
        #pragma unroll
        for (int t = 0; t < 8; ++t) { if (t <= ic) { pi += vi[t]; pf += vf[t]; } }
        float suf_i = si - pi + vi[ic];
        float suf_f = sf - pf + vf[ic];
        float civ, cfv;
        if (nc < 8) { civ = pi / si;    cfv = suf_f / sf; }
        else        { civ = suf_i / si; cfv = pf / sf;    }
        ci_s[tid] = civ; cf_s[tid] = cfv;
    }

    const __bf16* Arow = Abf + (size_t)(bm * BM) * K_TOT;
    const __bf16* Wblk = Wp  + (size_t)bh * 256 * K_TOT;
    __bf16* const A0p = lds;
    __bf16* const A1p = lds + 16384;
    __bf16* const B0p = lds + 32768;
    __bf16* const B1p = lds + 49152;

    // prologue staging: A(0)->A0, B(0)->B0, B(1)->B1
    stage_half(Arow, 0,  A0p,        0,   tid);
    stage_half(Arow, 0,  A0p + 8192, 128, tid);
    stage_half(Wblk, 0,  B0p,        0,   tid);
    stage_half(Wblk, 0,  B0p + 8192, 128, tid);
    stage_half(Wblk, BK, B1p,        0,   tid);
    stage_half(Wblk, BK, B1p + 8192, 128, tid);
    asm volatile("s_waitcnt lgkmcnt(0)" ::: "memory");   // ci/bias ds_writes done
    asm volatile("s_waitcnt vmcnt(4)"   ::: "memory");   // A(0),B(0) done; B(1) in flight
    __builtin_amdgcn_s_barrier();
    asm volatile("" ::: "memory");

    f32x4  acc[8][4];
    #pragma unroll
    for (int i = 0; i < 8; ++i)
        #pragma unroll
        for (int j = 0; j < 4; ++j) acc[i][j] = (f32x4){0.f, 0.f, 0.f, 0.f};
    bf16x8 afE[2][2], afO[2][2];
    bf16x8 bfr[4][2];

    const int l    = tid & 63;
    const int wid  = tid >> 6;        // 0..7
    const int wrw  = wid >> 2;        // 0..1  (M)
    const int wc   = wid & 3;         // 0..3  (N)
    const int lr   = l & 15;
    const int lh   = l >> 4;
    const int wrow = wrw * 128;
    const int wcol = wc * 64;

    #pragma unroll 1
    for (int it = 0; it < NKT / 2; ++it) {
        const int t = 2 * it;
        TILE11(t,     A0p, A1p, B0p);
        TILE11(t + 1, A1p, A0p, B1p);
    }
    asm volatile("s_waitcnt vmcnt(0) lgkmcnt(0)" ::: "memory");

    // ---- epilogue: all 4 gates of (b,h) lane-local (fn = gate) ----
    const size_t CY_OFF = (size_t)B_ROWS * H_DIM;
    const int hcol = h0 + wc * 16 + lr;
    #pragma unroll
    for (int m = 0; m < 8; ++m) {
        #pragma unroll
        for (int r = 0; r < 4; ++r) {
            int rt = wrow + m * 16 + lh * 4 + r;
            int b  = bm * BM + rt;
            float civ = ci_s[rt], cfv = cf_s[rt];
            float ovl = cfv * civ;
            float og = acc[m][0][r] + bias_s[wcol + lr];
            float cg = acc[m][1][r] + bias_s[wcol + 16 + lr];
            float ig = acc[m][2][r] + bias_s[wcol + 32 + lr];
            float fg = acc[m][3][r] + bias_s[wcol + 48 + lr];
            float i_s = sigmoidf_(ig);
            float f_s = sigmoidf_(fg);
            float c_t = tanhf_(cg);
            float o_s = sigmoidf_(og);
            float fq = f_s * ovl + (cfv - ovl);
            float iq = i_s * ovl + (civ - ovl);
            float cxv = cx[(size_t)b * H_DIM + hcol];
            float cyv = fq * cxv + iq * c_t;
            float hyv = o_s * tanhf_(cyv);
            out[(size_t)b * H_DIM + hcol] = hyv;
            out[CY_OFF + (size_t)b * H_DIM + hcol] = cyv;
        }
    }
}

extern "C" void kernel_launch(void* const* d_in, const int* in_sizes, int n_in,
                              void* d_out, int out_size, void* d_ws, size_t ws_size,
                              hipStream_t stream) {
    const float* x            = (const float*)d_in[0];
    const float* hx           = (const float*)d_in[1];
    const float* cx           = (const float*)d_in[2];
    const float* input_floor  = (const float*)d_in[3];
    const float* forget_floor = (const float*)d_in[4];
    const float* W_ih         = (const float*)d_in[5];
    const float* b_ih         = (const float*)d_in[6];
    const float* W_hh         = (const float*)d_in[7];
    const float* b_hh         = (const float*)d_in[8];
    float* out = (float*)d_out;

    __bf16* Abf = (__bf16*)d_ws;
    __bf16* Wp  = (__bf16*)((char*)d_ws + A_PACK_BYTES);
    pack_AW<<<B_ROWS + 16 * 256, 256, 0, stream>>>(x, hx, W_ih, W_hh, Abf, Wp);
    onlstm_gemm11<<<512, THREADS, 0, stream>>>(
        Abf, Wp, cx, input_floor, forget_floor, b_ih, b_hh, out);
}